// Round 1
// baseline (648.092 us; speedup 1.0000x reference)
//
#include <hip/hip_runtime.h>

#define N_ROWS 32768   // 32 * 32 * 32  (B*H*W)
#define K_CODES 1024
#define CDIM 256

// ---------------- codebook norms: ||e_k||^2 ----------------
__global__ __launch_bounds__(64) void cb_norms(const float* __restrict__ cb,
                                               float* __restrict__ cbn) {
    int k = blockIdx.x;
    int lane = threadIdx.x;           // 0..63, 64*4 = 256 floats per row
    float4 v = reinterpret_cast<const float4*>(cb + k * CDIM)[lane];
    float s = v.x * v.x + v.y * v.y + v.z * v.z + v.w * v.w;
    #pragma unroll
    for (int off = 32; off > 0; off >>= 1) s += __shfl_down(s, off);
    if (lane == 0) cbn[k] = s;
}

// ---------------- GEMM + argmin ----------------
// Block: 256 threads (16x16), tile: 64 rows x 64 codes, channel tile 32.
// score(n,k) = ||e_k||^2 - 2 * z_n . e_k   (row norm dropped: constant per n)
__global__ __launch_bounds__(256) void vq_argmin(const float* __restrict__ z,
                                                 const float* __restrict__ cb,
                                                 const float* __restrict__ cbn,
                                                 int* __restrict__ idx_out) {
    __shared__ float As[32][64];   // [c][row]   8 KB
    __shared__ float Bs[32][64];   // [c][code]  8 KB
    __shared__ float rv[64][16];   // reduction vals
    __shared__ int   ri[64][16];   // reduction idxs

    const int tid = threadIdx.x;
    const int tx = tid & 15;       // code dir
    const int ty = tid >> 4;       // row dir
    const int rowBase = blockIdx.x * 64;   // 512 blocks; 64 consecutive n share batch b
    const int bb = rowBase >> 10;          // batch index
    const int hwBase = rowBase & 1023;     // h*32+w base

    float minv[4];
    int   mini[4];
    #pragma unroll
    for (int i = 0; i < 4; i++) { minv[i] = 3.4e38f; mini[i] = 0; }

    for (int kt = 0; kt < K_CODES; kt += 64) {
        float acc[4][4];
        #pragma unroll
        for (int i = 0; i < 4; i++)
            #pragma unroll
            for (int j = 0; j < 4; j++) acc[i][j] = 0.f;

        for (int ct = 0; ct < CDIM; ct += 32) {
            // A tile: z_flat[rowBase+r][ct+c] = z[((bb*256 + ct+c)<<10) + hwBase + r]
            // consecutive tid -> consecutive r -> coalesced 256B/64-lane
            #pragma unroll
            for (int l = 0; l < 8; l++) {
                int e = tid + l * 256;
                int r = e & 63, c = e >> 6;
                As[c][r] = z[((bb * 256 + ct + c) << 10) + hwBase + r];
            }
            // B tile: codebook[kt+k][ct+c], row-major contiguous in c
            #pragma unroll
            for (int l = 0; l < 8; l++) {
                int e = tid + l * 256;
                int c = e & 31, k = e >> 5;
                Bs[c][k] = cb[(kt + k) * CDIM + ct + c];
            }
            __syncthreads();
            #pragma unroll
            for (int c = 0; c < 32; c++) {
                float4 a  = *reinterpret_cast<const float4*>(&As[c][ty * 4]);
                float4 bv = *reinterpret_cast<const float4*>(&Bs[c][tx * 4]);
                float av[4] = {a.x, a.y, a.z, a.w};
                float bw[4] = {bv.x, bv.y, bv.z, bv.w};
                #pragma unroll
                for (int i = 0; i < 4; i++)
                    #pragma unroll
                    for (int j = 0; j < 4; j++)
                        acc[i][j] = fmaf(av[i], bw[j], acc[i][j]);
            }
            __syncthreads();
        }
        // fold this code tile into the running per-thread argmin
        // codes visited in ascending order -> strict < keeps first occurrence
        #pragma unroll
        for (int j = 0; j < 4; j++) {
            int code = kt + tx * 4 + j;
            float nrm = cbn[code];
            #pragma unroll
            for (int i = 0; i < 4; i++) {
                float d = fmaf(-2.f, acc[i][j], nrm);
                if (d < minv[i]) { minv[i] = d; mini[i] = code; }
            }
        }
    }

    // cross-thread (tx) reduction per row; lexicographic (val, idx) to match
    // jnp.argmin first-min tie-break
    #pragma unroll
    for (int i = 0; i < 4; i++) {
        rv[ty * 4 + i][tx] = minv[i];
        ri[ty * 4 + i][tx] = mini[i];
    }
    __syncthreads();
    if (tid < 64) {
        float bv = rv[tid][0]; int bi = ri[tid][0];
        #pragma unroll
        for (int t = 1; t < 16; t++) {
            float v = rv[tid][t]; int ii = ri[tid][t];
            if (v < bv || (v == bv && ii < bi)) { bv = v; bi = ii; }
        }
        idx_out[rowBase + tid] = bi;
    }
}

// ---------------- one-hot fill (writes ALL 134 MB, incl. zeros) ----------------
__global__ __launch_bounds__(256) void onehot_fill(const int* __restrict__ idx,
                                                   float* __restrict__ out) {
    int i = blockIdx.x * 256 + threadIdx.x;  // over N*K/4 float4s
    int n  = i >> 8;                         // 256 float4 per row
    int k4 = (i & 255) << 2;
    int id = idx[n];
    float4 v;
    v.x = (k4     == id) ? 1.f : 0.f;
    v.y = (k4 + 1 == id) ? 1.f : 0.f;
    v.z = (k4 + 2 == id) ? 1.f : 0.f;
    v.w = (k4 + 3 == id) ? 1.f : 0.f;
    reinterpret_cast<float4*>(out)[i] = v;
}

// ---------------- z_quantized gather, (B,C,H,W) layout ----------------
__global__ __launch_bounds__(256) void zq_fill(const int* __restrict__ idx,
                                               const float* __restrict__ cb,
                                               float* __restrict__ out) {
    int i  = blockIdx.x * 256 + threadIdx.x;  // 8388608 elements
    int hw = i & 1023;
    int c  = (i >> 10) & 255;
    int b  = i >> 18;
    int n  = (b << 10) | hw;
    out[i] = cb[idx[n] * CDIM + c];           // coalesced store; gather hits L2 (cb = 1 MB)
}

extern "C" void kernel_launch(void* const* d_in, const int* in_sizes, int n_in,
                              void* d_out, int out_size, void* d_ws, size_t ws_size,
                              hipStream_t stream) {
    const float* z  = (const float*)d_in[0];   // (32,256,32,32)
    const float* cb = (const float*)d_in[1];   // (1024,256)
    float* out0 = (float*)d_out;                         // one-hot: 32768*1024
    float* out1 = out0 + (size_t)N_ROWS * K_CODES;       // z_quantized: 8388608

    float* cbn = (float*)d_ws;                           // 1024 floats
    int*   idx = (int*)((char*)d_ws + 4096);             // 32768 ints

    cb_norms<<<K_CODES, 64, 0, stream>>>(cb, cbn);
    vq_argmin<<<N_ROWS / 64, 256, 0, stream>>>(z, cb, cbn, idx);
    onehot_fill<<<(N_ROWS * K_CODES / 4) / 256, 256, 0, stream>>>(idx, out0);
    zq_fill<<<(N_ROWS * CDIM) / 256, 256, 0, stream>>>(idx, cb, out1);
}

// Round 2
// 406.246 us; speedup vs baseline: 1.5953x; 1.5953x over previous
//
#include <hip/hip_runtime.h>

#define N_ROWS 32768   // 32 * 32 * 32  (B*H*W)
#define K_CODES 1024
#define CDIM 256

// ---------------- codebook norms: ||e_k||^2 ----------------
__global__ __launch_bounds__(64) void cb_norms(const float* __restrict__ cb,
                                               float* __restrict__ cbn) {
    int k = blockIdx.x;
    int lane = threadIdx.x;           // 0..63, 64*4 = 256 floats per row
    float4 v = reinterpret_cast<const float4*>(cb + k * CDIM)[lane];
    float s = v.x * v.x + v.y * v.y + v.z * v.z + v.w * v.w;
    #pragma unroll
    for (int off = 32; off > 0; off >>= 1) s += __shfl_down(s, off);
    if (lane == 0) cbn[k] = s;
}

// ---------------- codebook transpose: cbt[c][k] = cb[k][c] ----------------
__global__ __launch_bounds__(256) void cb_transpose(const float* __restrict__ cb,
                                                    float* __restrict__ cbt) {
    __shared__ float t[32][33];
    int k0 = (blockIdx.x & 31) * 32;   // 1024/32
    int c0 = (blockIdx.x >> 5) * 32;   // 256/32
    int lane = threadIdx.x & 31;
    int row = threadIdx.x >> 5;        // 0..7
    #pragma unroll
    for (int s = 0; s < 4; s++) {
        int r = row + s * 8;
        t[r][lane] = cb[(k0 + r) * CDIM + c0 + lane];   // coalesced read along c
    }
    __syncthreads();
    #pragma unroll
    for (int s = 0; s < 4; s++) {
        int r = row + s * 8;           // c-offset within tile
        cbt[(c0 + r) * K_CODES + k0 + lane] = t[lane][r]; // coalesced write along k
    }
}

// ---------------- GEMM + argmin ----------------
// 512 threads, tile 128 rows x 256 codes, microtile 8x8, c-chunk 64.
// score(n,k) = ||e_k||^2 - 2 * z_n . e_k   (row norm dropped: constant per n)
// LDS layouts chosen so every ds op is canonical (consecutive lanes ->
// consecutive float4) or a broadcast: zero bank conflicts by construction.
__global__ __launch_bounds__(512, 2) void vq_argmin(const float* __restrict__ z,
                                                    const float* __restrict__ cbt,
                                                    const float* __restrict__ cbn,
                                                    int* __restrict__ idx_out) {
    __shared__ float As[64][128];   // [c][row]  32 KB
    __shared__ float Bs[64][256];   // [c][code] 64 KB

    const int tid = threadIdx.x;
    const int tx = tid & 31;        // code dir (32 lanes)
    const int ty = tid >> 5;        // row dir  (0..15)
    const int rowBase = blockIdx.x * 128;   // 256 blocks
    const int bb = rowBase >> 10;           // batch index (128 | 1024)
    const int hwBase = rowBase & 1023;

    // thread's 8 rows: {ty*4+i, 64+ty*4+i}; 8 codes/kt-tile: {tx*4+j, 128+tx*4+j}
    float minv[8];
    int   mini[8];
    #pragma unroll
    for (int i = 0; i < 8; i++) { minv[i] = 3.4e38f; mini[i] = 0; }

    for (int kt = 0; kt < K_CODES; kt += 256) {
        float acc[2][2][4][4];   // [ri][ci][i][j]
        #pragma unroll
        for (int a = 0; a < 2; a++)
            #pragma unroll
            for (int b = 0; b < 2; b++)
                #pragma unroll
                for (int i = 0; i < 4; i++)
                    #pragma unroll
                    for (int j = 0; j < 4; j++) acc[a][b][i][j] = 0.f;

        for (int ccb = 0; ccb < CDIM; ccb += 64) {
            // stage A: 64c x 128r = 2048 float4; lanes -> consecutive r4 (canonical)
            #pragma unroll
            for (int l = 0; l < 4; l++) {
                int f = tid + l * 512;
                int r4 = f & 31, c = f >> 5;
                float4 v = *reinterpret_cast<const float4*>(
                    &z[((bb * 256 + ccb + c) << 10) + hwBase + r4 * 4]);
                *reinterpret_cast<float4*>(&As[c][r4 * 4]) = v;
            }
            // stage B from transposed codebook: lanes -> consecutive k4 (canonical)
            #pragma unroll
            for (int l = 0; l < 8; l++) {
                int f = tid + l * 512;
                int k4 = f & 63, c = f >> 6;
                float4 v = *reinterpret_cast<const float4*>(
                    &cbt[(ccb + c) * K_CODES + kt + k4 * 4]);
                *reinterpret_cast<float4*>(&Bs[c][k4 * 4]) = v;
            }
            __syncthreads();
            #pragma unroll 4
            for (int c = 0; c < 64; c++) {
                float4 a0 = *reinterpret_cast<const float4*>(&As[c][ty * 4]);
                float4 a1 = *reinterpret_cast<const float4*>(&As[c][64 + ty * 4]);
                float4 b0 = *reinterpret_cast<const float4*>(&Bs[c][tx * 4]);
                float4 b1 = *reinterpret_cast<const float4*>(&Bs[c][128 + tx * 4]);
                float av[2][4] = {{a0.x, a0.y, a0.z, a0.w}, {a1.x, a1.y, a1.z, a1.w}};
                float bw[2][4] = {{b0.x, b0.y, b0.z, b0.w}, {b1.x, b1.y, b1.z, b1.w}};
                #pragma unroll
                for (int ri = 0; ri < 2; ri++)
                    #pragma unroll
                    for (int i = 0; i < 4; i++)
                        #pragma unroll
                        for (int ci = 0; ci < 2; ci++)
                            #pragma unroll
                            for (int j = 0; j < 4; j++)
                                acc[ri][ci][i][j] =
                                    fmaf(av[ri][i], bw[ci][j], acc[ri][ci][i][j]);
            }
            __syncthreads();
        }
        // fold this 256-code tile; codes visited ascending -> strict < keeps
        // first occurrence (jnp.argmin tie-break)
        #pragma unroll
        for (int ci = 0; ci < 2; ci++)
            #pragma unroll
            for (int j = 0; j < 4; j++) {
                int code = kt + ci * 128 + tx * 4 + j;
                float nrm = cbn[code];   // lanes tx,j -> consecutive: coalesced
                #pragma unroll
                for (int ri = 0; ri < 2; ri++)
                    #pragma unroll
                    for (int i = 0; i < 4; i++) {
                        float d = fmaf(-2.f, acc[ri][ci][i][j], nrm);
                        int r = ri * 4 + i;
                        if (d < minv[r]) { minv[r] = d; mini[r] = code; }
                    }
            }
    }

    // cross-tx reduction per row (lexicographic (val,idx) = first-min tie-break)
    __syncthreads();
    float (*rv)[32] = reinterpret_cast<float(*)[32]>(&As[0][0]);   // 128x32 f
    int   (*rix)[32] = reinterpret_cast<int(*)[32]>(&As[32][0]);   // 128x32 i
    #pragma unroll
    for (int ri = 0; ri < 2; ri++)
        #pragma unroll
        for (int i = 0; i < 4; i++) {
            int row = ri * 64 + ty * 4 + i;
            rv[row][tx] = minv[ri * 4 + i];
            rix[row][tx] = mini[ri * 4 + i];
        }
    __syncthreads();
    if (tid < 128) {
        float bv = rv[tid][0]; int bi = rix[tid][0];
        #pragma unroll
        for (int t = 1; t < 32; t++) {
            float v = rv[tid][t]; int ii = rix[tid][t];
            if (v < bv || (v == bv && ii < bi)) { bv = v; bi = ii; }
        }
        idx_out[rowBase + tid] = bi;
    }
}

// ---------------- one-hot fill (writes ALL 134 MB, incl. zeros) ----------------
__global__ __launch_bounds__(256) void onehot_fill(const int* __restrict__ idx,
                                                   float* __restrict__ out) {
    int i = blockIdx.x * 256 + threadIdx.x;  // over N*K/4 float4s
    int n  = i >> 8;                         // 256 float4 per row
    int k4 = (i & 255) << 2;
    int id = idx[n];
    float4 v;
    v.x = (k4     == id) ? 1.f : 0.f;
    v.y = (k4 + 1 == id) ? 1.f : 0.f;
    v.z = (k4 + 2 == id) ? 1.f : 0.f;
    v.w = (k4 + 3 == id) ? 1.f : 0.f;
    reinterpret_cast<float4*>(out)[i] = v;
}

// ---------------- z_quantized gather, (B,C,H,W) layout ----------------
__global__ __launch_bounds__(256) void zq_fill(const int* __restrict__ idx,
                                               const float* __restrict__ cb,
                                               float* __restrict__ out) {
    int i  = blockIdx.x * 256 + threadIdx.x;  // 8388608 elements
    int hw = i & 1023;
    int c  = (i >> 10) & 255;
    int b  = i >> 18;
    int n  = (b << 10) | hw;
    out[i] = cb[idx[n] * CDIM + c];           // coalesced store; gather hits L2
}

extern "C" void kernel_launch(void* const* d_in, const int* in_sizes, int n_in,
                              void* d_out, int out_size, void* d_ws, size_t ws_size,
                              hipStream_t stream) {
    const float* z  = (const float*)d_in[0];   // (32,256,32,32)
    const float* cb = (const float*)d_in[1];   // (1024,256)
    float* out0 = (float*)d_out;                         // one-hot: 32768*1024
    float* out1 = out0 + (size_t)N_ROWS * K_CODES;       // z_quantized

    float* cbn = (float*)d_ws;                              // 4 KB
    int*   idx = (int*)((char*)d_ws + 4096);                // 128 KB
    float* cbt = (float*)((char*)d_ws + 4096 + 131072);     // 1 MB

    cb_norms<<<K_CODES, 64, 0, stream>>>(cb, cbn);
    cb_transpose<<<256, 256, 0, stream>>>(cb, cbt);
    vq_argmin<<<N_ROWS / 128, 512, 0, stream>>>(z, cbt, cbn, idx);
    onehot_fill<<<(N_ROWS * K_CODES / 4) / 256, 256, 0, stream>>>(idx, out0);
    zq_fill<<<(N_ROWS * CDIM) / 256, 256, 0, stream>>>(idx, cb, out1);
}

// Round 3
// 324.441 us; speedup vs baseline: 1.9976x; 1.2521x over previous
//
#include <hip/hip_runtime.h>

#define N_ROWS 32768   // 32 * 32 * 32  (B*H*W)
#define K_CODES 1024
#define CDIM 256

typedef _Float16 half8 __attribute__((ext_vector_type(8)));
typedef _Float16 half4 __attribute__((ext_vector_type(4)));
typedef float floatx4 __attribute__((ext_vector_type(4)));

// fast-path workspace layout (bytes)
#define WS_ZH   0ull
#define WS_ZL   16777216ull
#define WS_CBH  33554432ull
#define WS_CBL  34078720ull
#define WS_CBN  34603008ull
#define WS_PART 34607104ull
#define WS_IDX  36704256ull
#define WS_NEED 36835328ull

__device__ __forceinline__ void g2lds16(const void* g, void* l) {
    __builtin_amdgcn_global_load_lds(
        (const __attribute__((address_space(1))) void*)g,
        (__attribute__((address_space(3))) void*)l, 16, 0, 0);
}

// ================= fast path (fp16 hi/lo split + MFMA) =================

// codebook prep: scale by 32, split into fp16 hi/lo, norms of scaled values
__global__ __launch_bounds__(64) void cb_prep(const float* __restrict__ cb,
                                              _Float16* __restrict__ cbh,
                                              _Float16* __restrict__ cbl,
                                              float* __restrict__ cbn) {
    int k = blockIdx.x;
    int lane = threadIdx.x;
    float4 v = reinterpret_cast<const float4*>(cb + k * CDIM)[lane];
    float s0 = v.x * 32.f, s1 = v.y * 32.f, s2 = v.z * 32.f, s3 = v.w * 32.f;
    half4 hv, lv;
    hv[0] = (_Float16)s0; lv[0] = (_Float16)(s0 - (float)hv[0]);
    hv[1] = (_Float16)s1; lv[1] = (_Float16)(s1 - (float)hv[1]);
    hv[2] = (_Float16)s2; lv[2] = (_Float16)(s2 - (float)hv[2]);
    hv[3] = (_Float16)s3; lv[3] = (_Float16)(s3 - (float)hv[3]);
    *reinterpret_cast<half4*>(&cbh[k * CDIM + lane * 4]) = hv;
    *reinterpret_cast<half4*>(&cbl[k * CDIM + lane * 4]) = lv;
    float s = s0 * s0 + s1 * s1 + s2 * s2 + s3 * s3;
    #pragma unroll
    for (int off = 32; off > 0; off >>= 1) s += __shfl_down(s, off);
    if (lane == 0) cbn[k] = s;
}

// z prep: transpose (B,C,H,W) -> row-major (N=B*H*W, C), scale by 32, split
__global__ __launch_bounds__(256) void z_prep(const float* __restrict__ z,
                                              _Float16* __restrict__ zh,
                                              _Float16* __restrict__ zl) {
    __shared__ float t[64][68];
    int hwt = blockIdx.x & 15;
    int ct  = (blockIdx.x >> 4) & 3;
    int bb  = blockIdx.x >> 6;
    int tid = threadIdx.x;
    #pragma unroll
    for (int p = 0; p < 4; p++) {
        int e = p * 256 + tid;
        int c = e >> 4, h4 = e & 15;
        float4 v = *reinterpret_cast<const float4*>(
            &z[((bb * 256 + ct * 64 + c) << 10) + hwt * 64 + h4 * 4]);
        *reinterpret_cast<float4*>(&t[c][h4 * 4]) = v;
    }
    __syncthreads();
    #pragma unroll
    for (int p = 0; p < 4; p++) {
        int e = p * 256 + tid;
        int hw = e >> 4, c4 = e & 15;
        half4 hv, lv;
        #pragma unroll
        for (int j = 0; j < 4; j++) {
            float s = t[c4 * 4 + j][hw] * 32.f;
            _Float16 h = (_Float16)s;
            hv[j] = h;
            lv[j] = (_Float16)(s - (float)h);
        }
        size_t n = (size_t)(bb * 1024 + hwt * 64 + hw);
        *reinterpret_cast<half4*>(&zh[n * CDIM + ct * 64 + c4 * 4]) = hv;
        *reinterpret_cast<half4*>(&zl[n * CDIM + ct * 64 + c4 * 4]) = lv;
    }
}

// GEMM+argmin: block tile 128 rows x 128 codes, 4 waves (64x64 each),
// K-chunks of 32, fp16 MFMA, one fp32 acc for all 3 hi/lo combos.
// d_scaled(n,k) = ||32e||^2 - 2*(32z).(32e) = 1024*d_true (argmin invariant)
__global__ __launch_bounds__(256) void vq_mfma(
    const _Float16* __restrict__ zh, const _Float16* __restrict__ zl,
    const _Float16* __restrict__ cbh, const _Float16* __restrict__ cbl,
    const float* __restrict__ cbn, unsigned long long* __restrict__ partial) {

    // granule-major LDS: granule G=(q*128+r) holds 8 halves (16B), q=k/8
    __shared__ _Float16 AhL[4096], AlL[4096], BhL[4096], BlL[4096];
    __shared__ float rvv[128][2];
    __shared__ int   rcc[128][2];

    const int tid = threadIdx.x;
    const int lane = tid & 63, wave = tid >> 6;
    const int wm = wave & 1, wn = wave >> 1;   // wave tile: rows wm*64, codes wn*64
    const int fm = lane & 15, fq = lane >> 4;  // frag row/col & k-quad
    const int codeTile = blockIdx.x & 7;
    const int rowTile  = blockIdx.x >> 3;
    const int rowBase = rowTile * 128, codeBase = codeTile * 128;

    floatx4 acc[16];
    #pragma unroll
    for (int i = 0; i < 16; i++) acc[i] = (floatx4)0.f;

    for (int kc = 0; kc < CDIM; kc += 32) {
        #pragma unroll
        for (int i = 0; i < 2; i++) {
            int G = i * 256 + tid;          // wave-contiguous granules
            int q = G >> 7, r = G & 127;
            size_t ao = (size_t)(rowBase + r) * CDIM + kc + q * 8;
            size_t bo = (size_t)(codeBase + r) * CDIM + kc + q * 8;
            g2lds16(zh + ao,  &AhL[G * 8]);
            g2lds16(zl + ao,  &AlL[G * 8]);
            g2lds16(cbh + bo, &BhL[G * 8]);
            g2lds16(cbl + bo, &BlL[G * 8]);
        }
        __syncthreads();
        half8 ah[4], al[4], bh[4], bl[4];
        #pragma unroll
        for (int t = 0; t < 4; t++) {
            int ga = fq * 128 + wm * 64 + t * 16 + fm;
            int gb = fq * 128 + wn * 64 + t * 16 + fm;
            ah[t] = *reinterpret_cast<const half8*>(&AhL[ga * 8]);
            al[t] = *reinterpret_cast<const half8*>(&AlL[ga * 8]);
            bh[t] = *reinterpret_cast<const half8*>(&BhL[gb * 8]);
            bl[t] = *reinterpret_cast<const half8*>(&BlL[gb * 8]);
        }
        #pragma unroll
        for (int i = 0; i < 4; i++)
            #pragma unroll
            for (int j = 0; j < 4; j++) {
                acc[i*4+j] = __builtin_amdgcn_mfma_f32_16x16x32_f16(ah[i], bh[j], acc[i*4+j], 0, 0, 0);
                acc[i*4+j] = __builtin_amdgcn_mfma_f32_16x16x32_f16(al[i], bh[j], acc[i*4+j], 0, 0, 0);
                acc[i*4+j] = __builtin_amdgcn_mfma_f32_16x16x32_f16(ah[i], bl[j], acc[i*4+j], 0, 0, 0);
            }
        __syncthreads();
    }

    // epilogue: d = cbn - 2*acc; per-row argmin.
    // C/D layout: col = lane&15, row = (lane>>4)*4 + reg  [m89-verified]
    float cbnv[4];
    #pragma unroll
    for (int j = 0; j < 4; j++) cbnv[j] = cbn[codeBase + wn * 64 + j * 16 + fm];

    float bv[16]; int bc[16];
    #pragma unroll
    for (int i = 0; i < 4; i++)
        #pragma unroll
        for (int r = 0; r < 4; r++) {
            float best = 3.4e38f; int bcode = 0x7fffffff;
            #pragma unroll
            for (int j = 0; j < 4; j++) {   // ascending code: strict < = first-min
                float d = fmaf(-2.f, acc[i*4+j][r], cbnv[j]);
                int code = codeBase + wn * 64 + j * 16 + fm;
                if (d < best) { best = d; bcode = code; }
            }
            bv[i*4+r] = best; bc[i*4+r] = bcode;
        }
    // butterfly across the 16 lanes of each quad (lexicographic (val, code))
    #pragma unroll
    for (int s = 0; s < 16; s++) {
        float v = bv[s]; int c = bc[s];
        #pragma unroll
        for (int m = 1; m < 16; m <<= 1) {
            float ov = __shfl_xor(v, m, 64);
            int   oc = __shfl_xor(c, m, 64);
            if (ov < v || (ov == v && oc < c)) { v = ov; c = oc; }
        }
        bv[s] = v; bc[s] = c;
    }
    if (fm == 0) {
        #pragma unroll
        for (int i = 0; i < 4; i++)
            #pragma unroll
            for (int r = 0; r < 4; r++) {
                int row = wm * 64 + i * 16 + fq * 4 + r;
                rvv[row][wn] = bv[i*4+r];
                rcc[row][wn] = bc[i*4+r];
            }
    }
    __syncthreads();
    if (tid < 128) {
        float v0 = rvv[tid][0]; int c0 = rcc[tid][0];
        float v1 = rvv[tid][1]; int c1 = rcc[tid][1];
        if (v1 < v0 || (v1 == v0 && c1 < c0)) { v0 = v1; c0 = c1; }
        unsigned u = __float_as_uint(v0);
        u = (u & 0x80000000u) ? ~u : (u | 0x80000000u);   // monotone map
        partial[(size_t)(rowBase + tid) * 8 + codeTile] =
            ((unsigned long long)u << 32) | (unsigned)c0;
    }
}

__global__ __launch_bounds__(256) void vq_finalize(const unsigned long long* __restrict__ partial,
                                                   int* __restrict__ idx) {
    int row = blockIdx.x * 256 + threadIdx.x;
    unsigned long long best = partial[(size_t)row * 8];
    #pragma unroll
    for (int j = 1; j < 8; j++) {
        unsigned long long p = partial[(size_t)row * 8 + j];
        if (p < best) best = p;
    }
    idx[row] = (int)(best & 0xffffffffu);
}

// ================= fallback path (round-2 fp32 VALU, known-good) =================

__global__ __launch_bounds__(64) void cb_norms(const float* __restrict__ cb,
                                               float* __restrict__ cbn) {
    int k = blockIdx.x;
    int lane = threadIdx.x;
    float4 v = reinterpret_cast<const float4*>(cb + k * CDIM)[lane];
    float s = v.x * v.x + v.y * v.y + v.z * v.z + v.w * v.w;
    #pragma unroll
    for (int off = 32; off > 0; off >>= 1) s += __shfl_down(s, off);
    if (lane == 0) cbn[k] = s;
}

__global__ __launch_bounds__(256) void cb_transpose(const float* __restrict__ cb,
                                                    float* __restrict__ cbt) {
    __shared__ float t[32][33];
    int k0 = (blockIdx.x & 31) * 32;
    int c0 = (blockIdx.x >> 5) * 32;
    int lane = threadIdx.x & 31;
    int row = threadIdx.x >> 5;
    #pragma unroll
    for (int s = 0; s < 4; s++) {
        int r = row + s * 8;
        t[r][lane] = cb[(k0 + r) * CDIM + c0 + lane];
    }
    __syncthreads();
    #pragma unroll
    for (int s = 0; s < 4; s++) {
        int r = row + s * 8;
        cbt[(c0 + r) * K_CODES + k0 + lane] = t[lane][r];
    }
}

__global__ __launch_bounds__(512, 2) void vq_argmin(const float* __restrict__ z,
                                                    const float* __restrict__ cbt,
                                                    const float* __restrict__ cbn,
                                                    int* __restrict__ idx_out) {
    __shared__ float As[64][128];
    __shared__ float Bs[64][256];

    const int tid = threadIdx.x;
    const int tx = tid & 31;
    const int ty = tid >> 5;
    const int rowBase = blockIdx.x * 128;
    const int bb = rowBase >> 10;
    const int hwBase = rowBase & 1023;

    float minv[8];
    int   mini[8];
    #pragma unroll
    for (int i = 0; i < 8; i++) { minv[i] = 3.4e38f; mini[i] = 0; }

    for (int kt = 0; kt < K_CODES; kt += 256) {
        float acc[2][2][4][4];
        #pragma unroll
        for (int a = 0; a < 2; a++)
            #pragma unroll
            for (int b = 0; b < 2; b++)
                #pragma unroll
                for (int i = 0; i < 4; i++)
                    #pragma unroll
                    for (int j = 0; j < 4; j++) acc[a][b][i][j] = 0.f;

        for (int ccb = 0; ccb < CDIM; ccb += 64) {
            #pragma unroll
            for (int l = 0; l < 4; l++) {
                int f = tid + l * 512;
                int r4 = f & 31, c = f >> 5;
                float4 v = *reinterpret_cast<const float4*>(
                    &z[((bb * 256 + ccb + c) << 10) + hwBase + r4 * 4]);
                *reinterpret_cast<float4*>(&As[c][r4 * 4]) = v;
            }
            #pragma unroll
            for (int l = 0; l < 8; l++) {
                int f = tid + l * 512;
                int k4 = f & 63, c = f >> 6;
                float4 v = *reinterpret_cast<const float4*>(
                    &cbt[(ccb + c) * K_CODES + kt + k4 * 4]);
                *reinterpret_cast<float4*>(&Bs[c][k4 * 4]) = v;
            }
            __syncthreads();
            #pragma unroll 4
            for (int c = 0; c < 64; c++) {
                float4 a0 = *reinterpret_cast<const float4*>(&As[c][ty * 4]);
                float4 a1 = *reinterpret_cast<const float4*>(&As[c][64 + ty * 4]);
                float4 b0 = *reinterpret_cast<const float4*>(&Bs[c][tx * 4]);
                float4 b1 = *reinterpret_cast<const float4*>(&Bs[c][128 + tx * 4]);
                float av[2][4] = {{a0.x, a0.y, a0.z, a0.w}, {a1.x, a1.y, a1.z, a1.w}};
                float bw[2][4] = {{b0.x, b0.y, b0.z, b0.w}, {b1.x, b1.y, b1.z, b1.w}};
                #pragma unroll
                for (int ri = 0; ri < 2; ri++)
                    #pragma unroll
                    for (int i = 0; i < 4; i++)
                        #pragma unroll
                        for (int ci = 0; ci < 2; ci++)
                            #pragma unroll
                            for (int j = 0; j < 4; j++)
                                acc[ri][ci][i][j] =
                                    fmaf(av[ri][i], bw[ci][j], acc[ri][ci][i][j]);
            }
            __syncthreads();
        }
        #pragma unroll
        for (int ci = 0; ci < 2; ci++)
            #pragma unroll
            for (int j = 0; j < 4; j++) {
                int code = kt + ci * 128 + tx * 4 + j;
                float nrm = cbn[code];
                #pragma unroll
                for (int ri = 0; ri < 2; ri++)
                    #pragma unroll
                    for (int i = 0; i < 4; i++) {
                        float d = fmaf(-2.f, acc[ri][ci][i][j], nrm);
                        int r = ri * 4 + i;
                        if (d < minv[r]) { minv[r] = d; mini[r] = code; }
                    }
            }
    }

    __syncthreads();
    float (*rv)[32] = reinterpret_cast<float(*)[32]>(&As[0][0]);
    int   (*rix)[32] = reinterpret_cast<int(*)[32]>(&As[32][0]);
    #pragma unroll
    for (int ri = 0; ri < 2; ri++)
        #pragma unroll
        for (int i = 0; i < 4; i++) {
            int row = ri * 64 + ty * 4 + i;
            rv[row][tx] = minv[ri * 4 + i];
            rix[row][tx] = mini[ri * 4 + i];
        }
    __syncthreads();
    if (tid < 128) {
        float bvv = rv[tid][0]; int bii = rix[tid][0];
        #pragma unroll
        for (int t = 1; t < 32; t++) {
            float v = rv[tid][t]; int ii = rix[tid][t];
            if (v < bvv || (v == bvv && ii < bii)) { bvv = v; bii = ii; }
        }
        idx_out[rowBase + tid] = bii;
    }
}

// ================= output fills (shared by both paths) =================

__global__ __launch_bounds__(256) void onehot_fill(const int* __restrict__ idx,
                                                   float* __restrict__ out) {
    int i = blockIdx.x * 256 + threadIdx.x;
    int n  = i >> 8;
    int k4 = (i & 255) << 2;
    int id = idx[n];
    float4 v;
    v.x = (k4     == id) ? 1.f : 0.f;
    v.y = (k4 + 1 == id) ? 1.f : 0.f;
    v.z = (k4 + 2 == id) ? 1.f : 0.f;
    v.w = (k4 + 3 == id) ? 1.f : 0.f;
    reinterpret_cast<float4*>(out)[i] = v;
}

__global__ __launch_bounds__(256) void zq_fill(const int* __restrict__ idx,
                                               const float* __restrict__ cb,
                                               float* __restrict__ out) {
    int i  = blockIdx.x * 256 + threadIdx.x;
    int hw = i & 1023;
    int c  = (i >> 10) & 255;
    int b  = i >> 18;
    int n  = (b << 10) | hw;
    out[i] = cb[idx[n] * CDIM + c];
}

extern "C" void kernel_launch(void* const* d_in, const int* in_sizes, int n_in,
                              void* d_out, int out_size, void* d_ws, size_t ws_size,
                              hipStream_t stream) {
    const float* z  = (const float*)d_in[0];
    const float* cb = (const float*)d_in[1];
    float* out0 = (float*)d_out;
    float* out1 = out0 + (size_t)N_ROWS * K_CODES;

    if (ws_size >= WS_NEED) {
        _Float16* zh  = (_Float16*)((char*)d_ws + WS_ZH);
        _Float16* zl  = (_Float16*)((char*)d_ws + WS_ZL);
        _Float16* cbh = (_Float16*)((char*)d_ws + WS_CBH);
        _Float16* cbl = (_Float16*)((char*)d_ws + WS_CBL);
        float* cbn = (float*)((char*)d_ws + WS_CBN);
        unsigned long long* part = (unsigned long long*)((char*)d_ws + WS_PART);
        int* idx = (int*)((char*)d_ws + WS_IDX);

        cb_prep<<<K_CODES, 64, 0, stream>>>(cb, cbh, cbl, cbn);
        z_prep<<<2048, 256, 0, stream>>>(z, zh, zl);
        vq_mfma<<<2048, 256, 0, stream>>>(zh, zl, cbh, cbl, cbn, part);
        vq_finalize<<<N_ROWS / 256, 256, 0, stream>>>(part, idx);
        onehot_fill<<<(N_ROWS * K_CODES / 4) / 256, 256, 0, stream>>>(idx, out0);
        zq_fill<<<(N_ROWS * CDIM) / 256, 256, 0, stream>>>(idx, cb, out1);
    } else {
        float* cbn = (float*)d_ws;
        int*   idx = (int*)((char*)d_ws + 4096);
        float* cbt = (float*)((char*)d_ws + 4096 + 131072);

        cb_norms<<<K_CODES, 64, 0, stream>>>(cb, cbn);
        cb_transpose<<<256, 256, 0, stream>>>(cb, cbt);
        vq_argmin<<<N_ROWS / 128, 512, 0, stream>>>(z, cbt, cbn, idx);
        onehot_fill<<<(N_ROWS * K_CODES / 4) / 256, 256, 0, stream>>>(idx, out0);
        zq_fill<<<(N_ROWS * CDIM) / 256, 256, 0, stream>>>(idx, cb, out1);
    }
}

// Round 4
// 297.561 us; speedup vs baseline: 2.1780x; 1.0903x over previous
//
#include <hip/hip_runtime.h>

#define N_ROWS 32768   // 32 * 32 * 32  (B*H*W)
#define K_CODES 1024
#define CDIM 256

typedef _Float16 half8 __attribute__((ext_vector_type(8)));
typedef _Float16 half4 __attribute__((ext_vector_type(4)));
typedef float floatx16 __attribute__((ext_vector_type(16)));
typedef unsigned long long ull;

// fast-path workspace layout (bytes)
// zh/zl packed: [8 c-chunks][32768 n][32 halves]  (16 MB each)
// cbh/cbl packed: [8][1024][32]                   (512 KB each)
#define WS_ZH   0ull
#define WS_ZL   16777216ull
#define WS_CBH  33554432ull
#define WS_CBL  34078720ull
#define WS_CBN  34603008ull
#define WS_PART 34607104ull
#define WS_IDX  36704256ull
#define WS_NEED 36835328ull

__device__ __forceinline__ void g2lds16(const void* g, void* l) {
    __builtin_amdgcn_global_load_lds(
        (const __attribute__((address_space(1))) void*)g,
        (__attribute__((address_space(3))) void*)l, 16, 0, 0);
}

// ================= fast path (fp16 hi/lo split + 32x32 MFMA) =================

// codebook prep: scale by 32, split fp16 hi/lo into packed layout, norms
__global__ __launch_bounds__(64) void cb_prep(const float* __restrict__ cb,
                                              _Float16* __restrict__ cbh,
                                              _Float16* __restrict__ cbl,
                                              float* __restrict__ cbn) {
    int k = blockIdx.x;
    int lane = threadIdx.x;          // c = lane*4
    float4 v = reinterpret_cast<const float4*>(cb + k * CDIM)[lane];
    float s0 = v.x * 32.f, s1 = v.y * 32.f, s2 = v.z * 32.f, s3 = v.w * 32.f;
    half4 hv, lv;
    hv[0] = (_Float16)s0; lv[0] = (_Float16)(s0 - (float)hv[0]);
    hv[1] = (_Float16)s1; lv[1] = (_Float16)(s1 - (float)hv[1]);
    hv[2] = (_Float16)s2; lv[2] = (_Float16)(s2 - (float)hv[2]);
    hv[3] = (_Float16)s3; lv[3] = (_Float16)(s3 - (float)hv[3]);
    size_t off = (size_t)((lane >> 3) * K_CODES + k) * 32 + ((lane * 4) & 31);
    *reinterpret_cast<half4*>(&cbh[off]) = hv;
    *reinterpret_cast<half4*>(&cbl[off]) = lv;
    float s = s0 * s0 + s1 * s1 + s2 * s2 + s3 * s3;
    #pragma unroll
    for (int off2 = 32; off2 > 0; off2 >>= 1) s += __shfl_down(s, off2);
    if (lane == 0) cbn[k] = s;
}

// z prep: (B,C,H,W) -> packed [c/32][n][32], scale by 32, split hi/lo
__global__ __launch_bounds__(256) void z_prep(const float* __restrict__ z,
                                              _Float16* __restrict__ zh,
                                              _Float16* __restrict__ zl) {
    __shared__ float t[64][68];
    int hwt = blockIdx.x & 15;
    int ct  = (blockIdx.x >> 4) & 3;
    int bb  = blockIdx.x >> 6;
    int tid = threadIdx.x;
    #pragma unroll
    for (int p = 0; p < 4; p++) {
        int e = p * 256 + tid;
        int c = e >> 4, h4 = e & 15;
        float4 v = *reinterpret_cast<const float4*>(
            &z[((bb * 256 + ct * 64 + c) << 10) + hwt * 64 + h4 * 4]);
        *reinterpret_cast<float4*>(&t[c][h4 * 4]) = v;
    }
    __syncthreads();
    #pragma unroll
    for (int p = 0; p < 4; p++) {
        int e = p * 256 + tid;
        int hw = e >> 4, c4 = e & 15;
        half4 hv, lv;
        #pragma unroll
        for (int j = 0; j < 4; j++) {
            float s = t[c4 * 4 + j][hw] * 32.f;
            _Float16 h = (_Float16)s;
            hv[j] = h;
            lv[j] = (_Float16)(s - (float)h);
        }
        int n = bb * 1024 + hwt * 64 + hw;
        int cg = ct * 64 + c4 * 4;
        size_t off = (size_t)((cg >> 5) * N_ROWS + n) * 32 + (cg & 31);
        *reinterpret_cast<half4*>(&zh[off]) = hv;
        *reinterpret_cast<half4*>(&zl[off]) = lv;
    }
}

// GEMM+argmin: block 128 rows x 128 codes, 4 waves (64x64 each, 2x2 of 32x32),
// c-chunks of 32, 32x32x16 f16 MFMA, shared fp32 acc for 3 hi/lo terms.
// d_scaled(n,k) = ||32e||^2 - 2*(32z).(32e) = 1024*d_true (argmin invariant)
__global__ __launch_bounds__(256, 3) void vq_mfma32(
    const _Float16* __restrict__ zh, const _Float16* __restrict__ zl,
    const _Float16* __restrict__ cbh, const _Float16* __restrict__ cbl,
    const float* __restrict__ cbn, ull* __restrict__ partial) {

    // granule-major: granule g=(q*128+r) holds 8 halves (16B), q = (c%32)/8
    __shared__ _Float16 AhL[4096], AlL[4096], BhL[4096], BlL[4096];  // 8 KB ea
    __shared__ float rvv[128][2];
    __shared__ int   rcc[128][2];

    const int tid = threadIdx.x;
    const int lane = tid & 63, wave = tid >> 6;
    const int wm = wave & 1, wn = wave >> 1;   // wave: rows wm*64, codes wn*64
    const int fm = lane & 31, fq = lane >> 5;  // row/col in 32-tile, k-octet
    const int codeTile = blockIdx.x & 7;
    const int rowTile  = blockIdx.x >> 3;      // consecutive blocks share rowTile
    const int rowBase = rowTile * 128, codeBase = codeTile * 128;

    floatx16 acc[4];   // [i*2+j]: row-tile i (0/1 -> +0/+32), code-tile j
    #pragma unroll
    for (int i = 0; i < 4; i++) acc[i] = (floatx16)0.f;

    for (int kc = 0; kc < CDIM; kc += 32) {
        const int cc = kc >> 5;
        const size_t ab = (size_t)(cc * N_ROWS + rowBase) * 32;
        const size_t bb = (size_t)(cc * K_CODES + codeBase) * 32;
        #pragma unroll
        for (int i = 0; i < 2; i++) {
            int G = i * 256 + tid;              // 512 granules per buffer
            int q = G >> 7, r = G & 127;
            size_t so = (size_t)r * 32 + q * 8; // 64B-contig per row: line-friendly
            g2lds16(zh + ab + so,  &AhL[G * 8]);
            g2lds16(zl + ab + so,  &AlL[G * 8]);
            g2lds16(cbh + bb + so, &BhL[G * 8]);
            g2lds16(cbl + bb + so, &BlL[G * 8]);
        }
        __syncthreads();
        #pragma unroll
        for (int s = 0; s < 2; s++) {           // two k16 steps per chunk
            int q = s * 2 + fq;
            half8 ah[2], al[2], bh[2], bl[2];
            #pragma unroll
            for (int i = 0; i < 2; i++) {
                int ga = q * 128 + wm * 64 + i * 32 + fm;
                ah[i] = *reinterpret_cast<const half8*>(&AhL[ga * 8]);
                al[i] = *reinterpret_cast<const half8*>(&AlL[ga * 8]);
            }
            #pragma unroll
            for (int j = 0; j < 2; j++) {
                int gb = q * 128 + wn * 64 + j * 32 + fm;
                bh[j] = *reinterpret_cast<const half8*>(&BhL[gb * 8]);
                bl[j] = *reinterpret_cast<const half8*>(&BlL[gb * 8]);
            }
            #pragma unroll
            for (int i = 0; i < 2; i++)
                #pragma unroll
                for (int j = 0; j < 2; j++) {
                    acc[i*2+j] = __builtin_amdgcn_mfma_f32_32x32x16_f16(ah[i], bh[j], acc[i*2+j], 0, 0, 0);
                    acc[i*2+j] = __builtin_amdgcn_mfma_f32_32x32x16_f16(al[i], bh[j], acc[i*2+j], 0, 0, 0);
                    acc[i*2+j] = __builtin_amdgcn_mfma_f32_32x32x16_f16(ah[i], bl[j], acc[i*2+j], 0, 0, 0);
                }
        }
        __syncthreads();
    }

    // epilogue: d = cbn - 2*acc; argmin per row.
    // 32x32 C/D: col = lane&31, row = (reg&3) + 8*(reg>>2) + 4*(lane>>5)
    float cbnv[2];
    #pragma unroll
    for (int j = 0; j < 2; j++) cbnv[j] = cbn[codeBase + wn * 64 + j * 32 + fm];

    #pragma unroll
    for (int i = 0; i < 2; i++)
        #pragma unroll
        for (int r = 0; r < 16; r++) {
            float best = 3.4e38f; int bcode = 0x7fffffff;
            #pragma unroll
            for (int j = 0; j < 2; j++) {   // ascending code: strict < = first-min
                float d = fmaf(-2.f, acc[i*2+j][r], cbnv[j]);
                int code = codeBase + wn * 64 + j * 32 + fm;
                if (d < best) { best = d; bcode = code; }
            }
            // butterfly over the 32 lanes of this k-half (lex (val, code))
            #pragma unroll
            for (int m = 1; m < 32; m <<= 1) {
                float ov = __shfl_xor(best, m, 64);
                int   oc = __shfl_xor(bcode, m, 64);
                if (ov < best || (ov == best && oc < bcode)) { best = ov; bcode = oc; }
            }
            if (fm == 0) {
                int row = wm * 64 + i * 32 + (r & 3) + 8 * (r >> 2) + 4 * fq;
                rvv[row][wn] = best;
                rcc[row][wn] = bcode;
            }
        }
    __syncthreads();
    if (tid < 128) {
        float v0 = rvv[tid][0]; int c0 = rcc[tid][0];
        float v1 = rvv[tid][1]; int c1 = rcc[tid][1];
        if (v1 < v0 || (v1 == v0 && c1 < c0)) { v0 = v1; c0 = c1; }
        unsigned u = __float_as_uint(v0);
        u = (u & 0x80000000u) ? ~u : (u | 0x80000000u);   // monotone map
        partial[(size_t)(rowBase + tid) * 8 + codeTile] =
            ((ull)u << 32) | (unsigned)c0;
    }
}

// one-hot fill + cross-tile argmin finalize (one block per row)
__global__ __launch_bounds__(256) void onehot_fin(const ull* __restrict__ partial,
                                                  int* __restrict__ idx,
                                                  float* __restrict__ out) {
    int row = blockIdx.x;
    __shared__ int sid;
    if (threadIdx.x < 64) {
        ull v = (threadIdx.x < 8) ? partial[(size_t)row * 8 + threadIdx.x]
                                  : ~0ull;
        #pragma unroll
        for (int m = 1; m < 8; m <<= 1) {
            ull o = __shfl_xor(v, m, 64);
            if (o < v) v = o;
        }
        if (threadIdx.x == 0) {
            int id = (int)(v & 0xffffffffu);
            sid = id;
            idx[row] = id;
        }
    }
    __syncthreads();
    int id = sid;
    int k4 = threadIdx.x << 2;
    float4 v4;
    v4.x = (k4     == id) ? 1.f : 0.f;
    v4.y = (k4 + 1 == id) ? 1.f : 0.f;
    v4.z = (k4 + 2 == id) ? 1.f : 0.f;
    v4.w = (k4 + 3 == id) ? 1.f : 0.f;
    reinterpret_cast<float4*>(out)[(size_t)row * 256 + threadIdx.x] = v4;
}

// ---------------- z_quantized gather, (B,C,H,W) layout ----------------
__global__ __launch_bounds__(256) void zq_fill(const int* __restrict__ idx,
                                               const float* __restrict__ cb,
                                               float* __restrict__ out) {
    int i  = blockIdx.x * 256 + threadIdx.x;
    int hw = i & 1023;
    int c  = (i >> 10) & 255;
    int b  = i >> 18;
    int n  = (b << 10) | hw;
    out[i] = cb[idx[n] * CDIM + c];
}

// ================= fallback path (round-2 fp32 VALU, known-good) =================

__global__ __launch_bounds__(64) void cb_norms(const float* __restrict__ cb,
                                               float* __restrict__ cbn) {
    int k = blockIdx.x;
    int lane = threadIdx.x;
    float4 v = reinterpret_cast<const float4*>(cb + k * CDIM)[lane];
    float s = v.x * v.x + v.y * v.y + v.z * v.z + v.w * v.w;
    #pragma unroll
    for (int off = 32; off > 0; off >>= 1) s += __shfl_down(s, off);
    if (lane == 0) cbn[k] = s;
}

__global__ __launch_bounds__(256) void cb_transpose(const float* __restrict__ cb,
                                                    float* __restrict__ cbt) {
    __shared__ float t[32][33];
    int k0 = (blockIdx.x & 31) * 32;
    int c0 = (blockIdx.x >> 5) * 32;
    int lane = threadIdx.x & 31;
    int row = threadIdx.x >> 5;
    #pragma unroll
    for (int s = 0; s < 4; s++) {
        int r = row + s * 8;
        t[r][lane] = cb[(k0 + r) * CDIM + c0 + lane];
    }
    __syncthreads();
    #pragma unroll
    for (int s = 0; s < 4; s++) {
        int r = row + s * 8;
        cbt[(c0 + r) * K_CODES + k0 + lane] = t[lane][r];
    }
}

__global__ __launch_bounds__(512, 2) void vq_argmin(const float* __restrict__ z,
                                                    const float* __restrict__ cbt,
                                                    const float* __restrict__ cbn,
                                                    int* __restrict__ idx_out) {
    __shared__ float As[64][128];
    __shared__ float Bs[64][256];

    const int tid = threadIdx.x;
    const int tx = tid & 31;
    const int ty = tid >> 5;
    const int rowBase = blockIdx.x * 128;
    const int bb = rowBase >> 10;
    const int hwBase = rowBase & 1023;

    float minv[8];
    int   mini[8];
    #pragma unroll
    for (int i = 0; i < 8; i++) { minv[i] = 3.4e38f; mini[i] = 0; }

    for (int kt = 0; kt < K_CODES; kt += 256) {
        float acc[2][2][4][4];
        #pragma unroll
        for (int a = 0; a < 2; a++)
            #pragma unroll
            for (int b = 0; b < 2; b++)
                #pragma unroll
                for (int i = 0; i < 4; i++)
                    #pragma unroll
                    for (int j = 0; j < 4; j++) acc[a][b][i][j] = 0.f;

        for (int ccb = 0; ccb < CDIM; ccb += 64) {
            #pragma unroll
            for (int l = 0; l < 4; l++) {
                int f = tid + l * 512;
                int r4 = f & 31, c = f >> 5;
                float4 v = *reinterpret_cast<const float4*>(
                    &z[((bb * 256 + ccb + c) << 10) + hwBase + r4 * 4]);
                *reinterpret_cast<float4*>(&As[c][r4 * 4]) = v;
            }
            #pragma unroll
            for (int l = 0; l < 8; l++) {
                int f = tid + l * 512;
                int k4 = f & 63, c = f >> 6;
                float4 v = *reinterpret_cast<const float4*>(
                    &cbt[(ccb + c) * K_CODES + kt + k4 * 4]);
                *reinterpret_cast<float4*>(&Bs[c][k4 * 4]) = v;
            }
            __syncthreads();
            #pragma unroll 4
            for (int c = 0; c < 64; c++) {
                float4 a0 = *reinterpret_cast<const float4*>(&As[c][ty * 4]);
                float4 a1 = *reinterpret_cast<const float4*>(&As[c][64 + ty * 4]);
                float4 b0 = *reinterpret_cast<const float4*>(&Bs[c][tx * 4]);
                float4 b1 = *reinterpret_cast<const float4*>(&Bs[c][128 + tx * 4]);
                float av[2][4] = {{a0.x, a0.y, a0.z, a0.w}, {a1.x, a1.y, a1.z, a1.w}};
                float bw[2][4] = {{b0.x, b0.y, b0.z, b0.w}, {b1.x, b1.y, b1.z, b1.w}};
                #pragma unroll
                for (int ri = 0; ri < 2; ri++)
                    #pragma unroll
                    for (int i = 0; i < 4; i++)
                        #pragma unroll
                        for (int ci = 0; ci < 2; ci++)
                            #pragma unroll
                            for (int j = 0; j < 4; j++)
                                acc[ri][ci][i][j] =
                                    fmaf(av[ri][i], bw[ci][j], acc[ri][ci][i][j]);
            }
            __syncthreads();
        }
        #pragma unroll
        for (int ci = 0; ci < 2; ci++)
            #pragma unroll
            for (int j = 0; j < 4; j++) {
                int code = kt + ci * 128 + tx * 4 + j;
                float nrm = cbn[code];
                #pragma unroll
                for (int ri = 0; ri < 2; ri++)
                    #pragma unroll
                    for (int i = 0; i < 4; i++) {
                        float d = fmaf(-2.f, acc[ri][ci][i][j], nrm);
                        int r = ri * 4 + i;
                        if (d < minv[r]) { minv[r] = d; mini[r] = code; }
                    }
            }
    }

    __syncthreads();
    float (*rv)[32] = reinterpret_cast<float(*)[32]>(&As[0][0]);
    int   (*rix)[32] = reinterpret_cast<int(*)[32]>(&As[32][0]);
    #pragma unroll
    for (int ri = 0; ri < 2; ri++)
        #pragma unroll
        for (int i = 0; i < 4; i++) {
            int row = ri * 64 + ty * 4 + i;
            rv[row][tx] = minv[ri * 4 + i];
            rix[row][tx] = mini[ri * 4 + i];
        }
    __syncthreads();
    if (tid < 128) {
        float bvv = rv[tid][0]; int bii = rix[tid][0];
        #pragma unroll
        for (int t = 1; t < 32; t++) {
            float v = rv[tid][t]; int ii = rix[tid][t];
            if (v < bvv || (v == bvv && ii < bii)) { bvv = v; bii = ii; }
        }
        idx_out[rowBase + tid] = bii;
    }
}

__global__ __launch_bounds__(256) void onehot_fill(const int* __restrict__ idx,
                                                   float* __restrict__ out) {
    int i = blockIdx.x * 256 + threadIdx.x;
    int n  = i >> 8;
    int k4 = (i & 255) << 2;
    int id = idx[n];
    float4 v;
    v.x = (k4     == id) ? 1.f : 0.f;
    v.y = (k4 + 1 == id) ? 1.f : 0.f;
    v.z = (k4 + 2 == id) ? 1.f : 0.f;
    v.w = (k4 + 3 == id) ? 1.f : 0.f;
    reinterpret_cast<float4*>(out)[i] = v;
}

extern "C" void kernel_launch(void* const* d_in, const int* in_sizes, int n_in,
                              void* d_out, int out_size, void* d_ws, size_t ws_size,
                              hipStream_t stream) {
    const float* z  = (const float*)d_in[0];
    const float* cb = (const float*)d_in[1];
    float* out0 = (float*)d_out;
    float* out1 = out0 + (size_t)N_ROWS * K_CODES;

    if (ws_size >= WS_NEED) {
        _Float16* zh  = (_Float16*)((char*)d_ws + WS_ZH);
        _Float16* zl  = (_Float16*)((char*)d_ws + WS_ZL);
        _Float16* cbh = (_Float16*)((char*)d_ws + WS_CBH);
        _Float16* cbl = (_Float16*)((char*)d_ws + WS_CBL);
        float* cbn = (float*)((char*)d_ws + WS_CBN);
        ull* part = (ull*)((char*)d_ws + WS_PART);
        int* idx = (int*)((char*)d_ws + WS_IDX);

        cb_prep<<<K_CODES, 64, 0, stream>>>(cb, cbh, cbl, cbn);
        z_prep<<<2048, 256, 0, stream>>>(z, zh, zl);
        vq_mfma32<<<2048, 256, 0, stream>>>(zh, zl, cbh, cbl, cbn, part);
        onehot_fin<<<N_ROWS, 256, 0, stream>>>(part, idx, out0);
        zq_fill<<<(N_ROWS * CDIM) / 256, 256, 0, stream>>>(idx, cb, out1);
    } else {
        float* cbn = (float*)d_ws;
        int*   idx = (int*)((char*)d_ws + 4096);
        float* cbt = (float*)((char*)d_ws + 4096 + 131072);

        cb_norms<<<K_CODES, 64, 0, stream>>>(cb, cbn);
        cb_transpose<<<256, 256, 0, stream>>>(cb, cbt);
        vq_argmin<<<N_ROWS / 128, 512, 0, stream>>>(z, cbt, cbn, idx);
        onehot_fill<<<(N_ROWS * K_CODES / 4) / 256, 256, 0, stream>>>(idx, out0);
        zq_fill<<<(N_ROWS * CDIM) / 256, 256, 0, stream>>>(idx, cb, out1);
    }
}